// Round 3
// baseline (58704.047 us; speedup 1.0000x reference)
//
#include <hip/hip_runtime.h>

// DNADecoder: B=64,T=128,P=1024,D=512,F=2048,V=4096,L=4  (all fp32)
// Persistent-kernel decode: 8 independent groups x 32 blocks, 8 batch rows
// each, private device-memory barriers (13/step). Folds: cross-attn constant,
// self-attn Wfold=WvWo+I, E0=emb@Wfold0 lookup, argmax(softmax)=argmax.

#define B 64
#define T 128
#define PP 1024
#define D 512
#define F 2048
#define V 4096

typedef const float* fp;

static __device__ __forceinline__ float wred(float s){
    #pragma unroll
    for (int o = 32; o > 0; o >>= 1) s += __shfl_xor(s, o, 64);
    return s;
}

// ---------------- setup: protein -> mem1 -> per-layer cross-attn constant ----
__global__ __launch_bounds__(256) void k_setup_mem(
    fp prot, fp p1w, fp p1b, fp p2w, fp p2b,
    fp caw, fp cab, float* ca_out)
{
    __shared__ float xp[PP];
    __shared__ float hr[PP];
    __shared__ float m1[D];
    __shared__ float tv[D];
    int b = blockIdx.x, tid = threadIdx.x;
    for (int i = tid; i < PP; i += 256) xp[i] = prot[b*PP + i];
    __syncthreads();
    for (int c = tid; c < 1024; c += 256){
        float acc = p1b[c];
        for (int k = 0; k < PP; k++) acc = fmaf(xp[k], p1w[k*1024 + c], acc);
        hr[c] = fmaxf(acc, 0.f);
    }
    __syncthreads();
    for (int c = tid; c < D; c += 256){
        float acc = p2b[c];
        for (int k = 0; k < 1024; k++) acc = fmaf(hr[k], p2w[k*D + c], acc);
        m1[c] = acc;
    }
    __syncthreads();
    for (int l = 0; l < 4; l++){
        const float* wv = caw + (size_t)(l*4 + 2)*D*D;
        const float* bv = cab + (l*4 + 2)*D;
        for (int c = tid; c < D; c += 256){
            float acc = bv[c];
            for (int k = 0; k < D; k++) acc = fmaf(m1[k], wv[k*D + c], acc);
            tv[c] = acc;
        }
        __syncthreads();
        const float* wo = caw + (size_t)(l*4 + 3)*D*D;
        const float* bo = cab + (l*4 + 3)*D;
        for (int c = tid; c < D; c += 256){
            float acc = bo[c];
            for (int k = 0; k < D; k++) acc = fmaf(tv[k], wo[k*D + c], acc);
            ca_out[(l*B + b)*D + c] = acc;
        }
        __syncthreads();
    }
}

// ---------------- setup: fold self-attn  Wfold = Wv@Wo + I, bfold = bv@Wo+bo --
__global__ __launch_bounds__(256) void k_fold_sa(
    fp saw, fp sab, float* wfold, float* bfold)
{
    int l = blockIdx.x >> 6;
    int kb = blockIdx.x & 63;              // 8 rows of Wfold each
    int tid = threadIdx.x;
    const float* Wv = saw + (size_t)(l*4 + 2)*D*D;
    const float* Wo = saw + (size_t)(l*4 + 3)*D*D;
    __shared__ float a[8][D];
    for (int i = tid; i < 8*D; i += 256){
        int r = i >> 9, mm = i & 511;
        a[r][mm] = Wv[(kb*8 + r)*D + mm];
    }
    __syncthreads();
    for (int cc = 0; cc < 2; cc++){
        int c = tid + cc*256;
        float acc[8];
        #pragma unroll
        for (int r = 0; r < 8; r++) acc[r] = 0.f;
        for (int mm = 0; mm < D; mm++){
            float w = Wo[mm*D + c];
            #pragma unroll
            for (int r = 0; r < 8; r++) acc[r] = fmaf(a[r][mm], w, acc[r]);
        }
        #pragma unroll
        for (int r = 0; r < 8; r++){
            int kg = kb*8 + r;
            wfold[((size_t)l*D + kg)*D + c] = acc[r] + (kg == c ? 1.f : 0.f);
        }
    }
    if (kb == 0){
        const float* bv = sab + (l*4 + 2)*D;
        const float* bo = sab + (l*4 + 3)*D;
        for (int c = tid; c < D; c += 256){
            float acc = bo[c];
            for (int mm = 0; mm < D; mm++) acc = fmaf(bv[mm], Wo[mm*D + c], acc);
            bfold[l*D + c] = acc;
        }
    }
}

// ---------------- setup: E0 = emb @ wfold0  (4096x512) -----------------------
__global__ __launch_bounds__(256) void k_e0(fp emb, const float* wf0, float* E0){
    __shared__ float et[8*512];
    int v0 = blockIdx.x*8, tid = threadIdx.x;
    for (int i = tid; i < 1024; i += 256){
        int r = i >> 7, k4 = (i & 127)*4;
        *(float4*)(et + r*512 + k4) = *(const float4*)(emb + (size_t)(v0+r)*512 + k4);
    }
    __syncthreads();
    for (int half = 0; half < 2; half++){
        int c = tid + half*256;
        float acc[8] = {0,0,0,0,0,0,0,0};
        #pragma unroll 2
        for (int k4 = 0; k4 < 512; k4 += 4){
            float w0 = wf0[(size_t)(k4+0)*512 + c];
            float w1 = wf0[(size_t)(k4+1)*512 + c];
            float w2 = wf0[(size_t)(k4+2)*512 + c];
            float w3 = wf0[(size_t)(k4+3)*512 + c];
            #pragma unroll
            for (int r = 0; r < 8; r++){
                float4 xv = *(const float4*)(et + r*512 + k4);
                acc[r] = fmaf(xv.x, w0, fmaf(xv.y, w1, fmaf(xv.z, w2, fmaf(xv.w, w3, acc[r]))));
            }
        }
        #pragma unroll
        for (int r = 0; r < 8; r++) E0[(size_t)(v0+r)*512 + c] = acc[r];
    }
}

// ---------------- setup: peW = pe @ wfold0 + bfold0  (128x512) ---------------
__global__ __launch_bounds__(256) void k_pew(fp pe, const float* wf0, const float* bfold,
                                             float* peW){
    __shared__ float et[8*512];
    int t0 = blockIdx.x*8, tid = threadIdx.x;
    for (int i = tid; i < 1024; i += 256){
        int r = i >> 7, k4 = (i & 127)*4;
        *(float4*)(et + r*512 + k4) = *(const float4*)(pe + (size_t)(t0+r)*512 + k4);
    }
    __syncthreads();
    for (int half = 0; half < 2; half++){
        int c = tid + half*256;
        float acc[8] = {0,0,0,0,0,0,0,0};
        #pragma unroll 2
        for (int k4 = 0; k4 < 512; k4 += 4){
            float w0 = wf0[(size_t)(k4+0)*512 + c];
            float w1 = wf0[(size_t)(k4+1)*512 + c];
            float w2 = wf0[(size_t)(k4+2)*512 + c];
            float w3 = wf0[(size_t)(k4+3)*512 + c];
            #pragma unroll
            for (int r = 0; r < 8; r++){
                float4 xv = *(const float4*)(et + r*512 + k4);
                acc[r] = fmaf(xv.x, w0, fmaf(xv.y, w1, fmaf(xv.z, w2, fmaf(xv.w, w3, acc[r]))));
            }
        }
        float bb = bfold[c];
        #pragma unroll
        for (int r = 0; r < 8; r++) peW[(size_t)(t0+r)*512 + c] = acc[r] + bb;
    }
}

// ---------------- persistent decode kernel -----------------------------------
// lds layout: activations row-major lds[r*K + k] (K=512 region 0..4095,
// K=2048 region 0..16383 for FFN2), reduce scratch at 16384..18431.

__global__ __launch_bounds__(256) void k_decode(
    const float* wfold, const float* bfold, const float* E0, const float* peW,
    const float* ca_o, fp w1, fp b1, fp w2, fp b2, fp lng, fp lnb,
    fp outw, fp outb, const int* itok,
    float* u1buf, float* zbuf, float* hbuf, float* u3buf, float* lgt,
    int* tok, int* ctrl, float* out)
{
    const int g = blockIdx.x & 7, m = blockIdx.x >> 3;
    const int r0 = g*8;
    const int tid = threadIdx.x;
    const int lane = tid & 63, wv = tid >> 6;
    int* cnt = ctrl + g*64;
    int* go  = ctrl + g*64 + 16;
    int bk = 0;
    __shared__ float lds[18432];
    float* scratch = lds + 16384;

    #define GBAR() do {                                                          \
        bk++;                                                                    \
        __syncthreads();                                                         \
        if (tid == 0){                                                           \
            int v_ = __hip_atomic_fetch_add(cnt, 1, __ATOMIC_ACQ_REL,            \
                                            __HIP_MEMORY_SCOPE_AGENT);           \
            if ((v_ & 31) == 31)                                                 \
                __hip_atomic_store(go, bk, __ATOMIC_RELEASE,                     \
                                   __HIP_MEMORY_SCOPE_AGENT);                    \
            else                                                                 \
                while (__hip_atomic_load(go, __ATOMIC_ACQUIRE,                   \
                                         __HIP_MEMORY_SCOPE_AGENT) < bk)         \
                    __builtin_amdgcn_s_sleep(1);                                 \
        }                                                                        \
        __syncthreads();                                                         \
    } while (0)

    #pragma unroll 1
    for (int t = 0; t < T; t++){
        #pragma unroll 1
        for (int l = 0; l < 4; l++){
            // ---------- S1 (l>=1): x = LN(u3, ln[l-1][2]); u1 = x@wfold[l]+bfold
            if (l > 0){
                fp gg = lng + ((l-1)*3+2)*D, bb = lnb + ((l-1)*3+2)*D;
                #pragma unroll 1
                for (int h = 0; h < 2; h++){
                    int r = wv*2 + h;
                    const float* s = u3buf + (size_t)(r0 + r)*D;
                    float e[8], su = 0.f, sq = 0.f;
                    #pragma unroll
                    for (int j = 0; j < 8; j++){
                        float v = s[lane + j*64];
                        e[j] = v; su += v; sq += v*v;
                    }
                    su = wred(su); sq = wred(sq);
                    float mu = su*(1.f/D), rs = rsqrtf(sq*(1.f/D) - mu*mu + 1e-5f);
                    #pragma unroll
                    for (int j = 0; j < 8; j++){
                        int d = lane + j*64;
                        lds[r*512 + d] = (e[j]-mu)*rs*gg[d] + bb[d];
                    }
                }
                __syncthreads();
                int c = tid & 15, ks = tid >> 4;
                int col = m*16 + c;
                const float* W = wfold + (size_t)l*D*D + col;
                float acc[8] = {0,0,0,0,0,0,0,0};
                #pragma unroll 2
                for (int k4 = 0; k4 < 32; k4 += 4){
                    int kk = ks*32 + k4;
                    float w0 = W[(size_t)(kk+0)*D];
                    float w1_ = W[(size_t)(kk+1)*D];
                    float w2_ = W[(size_t)(kk+2)*D];
                    float w3_ = W[(size_t)(kk+3)*D];
                    #pragma unroll
                    for (int r = 0; r < 8; r++){
                        float4 xv = *(const float4*)(lds + r*512 + kk);
                        acc[r] = fmaf(xv.x, w0, fmaf(xv.y, w1_, fmaf(xv.z, w2_, fmaf(xv.w, w3_, acc[r]))));
                    }
                }
                float* sc = scratch + (ks*16 + c)*8;
                #pragma unroll
                for (int j = 0; j < 8; j++) sc[j] = acc[j];
                __syncthreads();
                if (tid < 128){
                    int cc = tid >> 3, r = tid & 7;
                    float s = 0.f;
                    #pragma unroll
                    for (int q = 0; q < 16; q++) s += scratch[(q*16 + cc)*8 + r];
                    int col2 = m*16 + cc;
                    u1buf[(size_t)(r0+r)*D + col2] = s + bfold[l*D + col2];
                }
                GBAR();
            }
            // ---------- S2: z = LN1(LN0(u1)+ca); h = relu(z@W1+b1)
            {
                fp g0 = lng + (l*3)*D,   b0 = lnb + (l*3)*D;
                fp g1 = lng + (l*3+1)*D, b1v = lnb + (l*3+1)*D;
                const int* ts = (t == 0) ? itok : tok;
                #pragma unroll 1
                for (int h = 0; h < 2; h++){
                    int r = wv*2 + h, rg = r0 + r;
                    float e[8], su = 0.f, sq = 0.f;
                    if (l == 0){
                        int tk = ts[rg];
                        const float* er = E0 + (size_t)tk*D;
                        const float* pr = peW + t*D;
                        #pragma unroll
                        for (int j = 0; j < 8; j++){
                            int d = lane + j*64;
                            float v = er[d] + pr[d];
                            e[j] = v; su += v; sq += v*v;
                        }
                    } else {
                        const float* s = u1buf + (size_t)rg*D;
                        #pragma unroll
                        for (int j = 0; j < 8; j++){
                            float v = s[lane + j*64];
                            e[j] = v; su += v; sq += v*v;
                        }
                    }
                    su = wred(su); sq = wred(sq);
                    float mu = su*(1.f/D), rs = rsqrtf(sq*(1.f/D) - mu*mu + 1e-5f);
                    const float* car = ca_o + ((size_t)l*B + rg)*D;
                    su = 0.f; sq = 0.f;
                    #pragma unroll
                    for (int j = 0; j < 8; j++){
                        int d = lane + j*64;
                        float v = (e[j]-mu)*rs*g0[d] + b0[d] + car[d];
                        e[j] = v; su += v; sq += v*v;
                    }
                    su = wred(su); sq = wred(sq);
                    float mu2 = su*(1.f/D), rs2 = rsqrtf(sq*(1.f/D) - mu2*mu2 + 1e-5f);
                    #pragma unroll
                    for (int j = 0; j < 8; j++){
                        int d = lane + j*64;
                        float z = (e[j]-mu2)*rs2*g1[d] + b1v[d];
                        lds[r*512 + d] = z;
                        if (m == 0) zbuf[(size_t)rg*D + d] = z;
                    }
                }
                __syncthreads();
                int c = tid & 63, ks = tid >> 6;
                int col = m*64 + c;
                const float* W = w1 + (size_t)l*D*F + col;
                float acc[8] = {0,0,0,0,0,0,0,0};
                #pragma unroll 2
                for (int k4 = 0; k4 < 128; k4 += 4){
                    int kk = ks*128 + k4;
                    float w0 = W[(size_t)(kk+0)*F];
                    float w1_ = W[(size_t)(kk+1)*F];
                    float w2_ = W[(size_t)(kk+2)*F];
                    float w3_ = W[(size_t)(kk+3)*F];
                    #pragma unroll
                    for (int r = 0; r < 8; r++){
                        float4 xv = *(const float4*)(lds + r*512 + kk);
                        acc[r] = fmaf(xv.x, w0, fmaf(xv.y, w1_, fmaf(xv.z, w2_, fmaf(xv.w, w3_, acc[r]))));
                    }
                }
                float* sc = scratch + (ks*64 + c)*8;
                #pragma unroll
                for (int j = 0; j < 8; j++) sc[j] = acc[j];
                __syncthreads();
                #pragma unroll
                for (int o = 0; o < 2; o++){
                    int idx = tid + o*256;
                    int cc = idx >> 3, r = idx & 7;
                    float s = 0.f;
                    #pragma unroll
                    for (int q = 0; q < 4; q++) s += scratch[(q*64 + cc)*8 + r];
                    int col2 = m*64 + cc;
                    s += b1[l*F + col2];
                    hbuf[(size_t)(r0+r)*F + col2] = fmaxf(s, 0.f);
                }
                GBAR();
            }
            // ---------- S3: u3 = z + h@W2 + b2
            {
                for (int i = tid; i < 4096; i += 256){
                    int r = i >> 9, k4 = (i & 511)*4;
                    *(float4*)(lds + r*2048 + k4) =
                        *(const float4*)(hbuf + (size_t)(r0+r)*F + k4);
                }
                __syncthreads();
                int c = tid & 15, ks = tid >> 4;
                int col = m*16 + c;
                const float* W = w2 + (size_t)l*F*D + col;
                float acc[8] = {0,0,0,0,0,0,0,0};
                #pragma unroll 2
                for (int k4 = 0; k4 < 128; k4 += 4){
                    int kk = ks*128 + k4;
                    float w0 = W[(size_t)(kk+0)*D];
                    float w1_ = W[(size_t)(kk+1)*D];
                    float w2_ = W[(size_t)(kk+2)*D];
                    float w3_ = W[(size_t)(kk+3)*D];
                    #pragma unroll
                    for (int r = 0; r < 8; r++){
                        float4 xv = *(const float4*)(lds + r*2048 + kk);
                        acc[r] = fmaf(xv.x, w0, fmaf(xv.y, w1_, fmaf(xv.z, w2_, fmaf(xv.w, w3_, acc[r]))));
                    }
                }
                __syncthreads();   // lds main region reuse done; scratch write next
                float* sc = scratch + (ks*16 + c)*8;
                #pragma unroll
                for (int j = 0; j < 8; j++) sc[j] = acc[j];
                __syncthreads();
                if (tid < 128){
                    int cc = tid >> 3, r = tid & 7;
                    float s = 0.f;
                    #pragma unroll
                    for (int q = 0; q < 16; q++) s += scratch[(q*16 + cc)*8 + r];
                    int col2 = m*16 + cc;
                    u3buf[(size_t)(r0+r)*D + col2] =
                        s + b2[l*D + col2] + zbuf[(size_t)(r0+r)*D + col2];
                }
                GBAR();
            }
        }
        // ---------- logits: x = LN(u3, ln[3][2]); lgt = x@outw + outb
        {
            fp gg = lng + 11*D, bb = lnb + 11*D;
            #pragma unroll 1
            for (int h = 0; h < 2; h++){
                int r = wv*2 + h;
                const float* s = u3buf + (size_t)(r0 + r)*D;
                float e[8], su = 0.f, sq = 0.f;
                #pragma unroll
                for (int j = 0; j < 8; j++){
                    float v = s[lane + j*64];
                    e[j] = v; su += v; sq += v*v;
                }
                su = wred(su); sq = wred(sq);
                float mu = su*(1.f/D), rs = rsqrtf(sq*(1.f/D) - mu*mu + 1e-5f);
                #pragma unroll
                for (int j = 0; j < 8; j++){
                    int d = lane + j*64;
                    lds[r*512 + d] = (e[j]-mu)*rs*gg[d] + bb[d];
                }
            }
            __syncthreads();
            int c = tid & 127, ks = tid >> 7;
            int col = m*128 + c;
            const float* W = outw + col;
            float acc[8] = {0,0,0,0,0,0,0,0};
            #pragma unroll 2
            for (int k4 = 0; k4 < 256; k4 += 4){
                int kk = ks*256 + k4;
                float w0 = W[(size_t)(kk+0)*V];
                float w1_ = W[(size_t)(kk+1)*V];
                float w2_ = W[(size_t)(kk+2)*V];
                float w3_ = W[(size_t)(kk+3)*V];
                #pragma unroll
                for (int r = 0; r < 8; r++){
                    float4 xv = *(const float4*)(lds + r*512 + kk);
                    acc[r] = fmaf(xv.x, w0, fmaf(xv.y, w1_, fmaf(xv.z, w2_, fmaf(xv.w, w3_, acc[r]))));
                }
            }
            float* sc = scratch + (ks*128 + c)*8;
            #pragma unroll
            for (int j = 0; j < 8; j++) sc[j] = acc[j];
            __syncthreads();
            #pragma unroll
            for (int o = 0; o < 4; o++){
                int idx = tid + o*256;
                int cc = idx >> 3, r = idx & 7;
                float s = scratch[cc*8 + r] + scratch[(128 + cc)*8 + r];
                int col2 = m*128 + cc;
                lgt[(size_t)(r0+r)*V + col2] = s + outb[col2];
            }
            GBAR();
        }
        // ---------- final: argmax -> tok, softmax -> out
        {
            if (m < 8){
                int r = r0 + m;
                const float* lr = lgt + (size_t)r*V;
                float mx = -3.4e38f; int mi = 0;
                for (int i = tid; i < V; i += 256){
                    float v = lr[i];
                    if (v > mx){ mx = v; mi = i; }
                }
                #pragma unroll
                for (int o = 32; o > 0; o >>= 1){
                    float om = __shfl_xor(mx, o, 64);
                    int   oi = __shfl_xor(mi, o, 64);
                    if (om > mx || (om == mx && oi < mi)){ mx = om; mi = oi; }
                }
                float* sm = scratch;
                int*   si = (int*)(scratch + 8);
                float* ssum = scratch + 16;
                if (lane == 0){ sm[wv] = mx; si[wv] = mi; }
                __syncthreads();
                if (tid == 0){
                    float bm = sm[0]; int bi = si[0];
                    #pragma unroll
                    for (int q = 1; q < 4; q++)
                        if (sm[q] > bm || (sm[q] == bm && si[q] < bi)){ bm = sm[q]; bi = si[q]; }
                    sm[0] = bm; tok[r] = bi;
                }
                __syncthreads();
                mx = sm[0];
                float s = 0.f;
                for (int i = tid; i < V; i += 256) s += expf(lr[i] - mx);
                s = wred(s);
                if (lane == 0) ssum[wv] = s;
                __syncthreads();
                float inv = 1.f/(ssum[0]+ssum[1]+ssum[2]+ssum[3]);
                float* orow = out + ((size_t)r*T + t)*V;
                for (int i = tid; i < V; i += 256) orow[i] = expf(lr[i] - mx)*inv;
            }
            GBAR();
        }
    }
    #undef GBAR
}

// ---------------------------------------------------------------------------
extern "C" void kernel_launch(void* const* d_in, const int* in_sizes, int n_in,
                              void* d_out, int out_size, void* d_ws, size_t ws_size,
                              hipStream_t stream)
{
    fp prot = (fp)d_in[0];
    const int* itok = (const int*)d_in[1];
    fp p1w=(fp)d_in[2], p1b=(fp)d_in[3], p2w=(fp)d_in[4], p2b=(fp)d_in[5];
    fp emb=(fp)d_in[6], saw=(fp)d_in[7], sab=(fp)d_in[8];
    fp caw=(fp)d_in[9], cab=(fp)d_in[10];
    fp w1=(fp)d_in[11], b1=(fp)d_in[12], w2=(fp)d_in[13], b2=(fp)d_in[14];
    fp lng=(fp)d_in[15], lnb=(fp)d_in[16];
    fp outw=(fp)d_in[17], outb=(fp)d_in[18], pe=(fp)d_in[19];

    char* w = (char*)d_ws;
    float* wfold = (float*)w;  w += (size_t)4*D*D*4;     // 4 MB
    float* bfold = (float*)w;  w += 4*D*4;
    float* ca_o  = (float*)w;  w += (size_t)4*B*D*4;     // 512 KB
    float* E0    = (float*)w;  w += (size_t)V*D*4;       // 8 MB
    float* peW   = (float*)w;  w += (size_t)T*D*4;       // 256 KB
    float* u1buf = (float*)w;  w += (size_t)B*D*4;
    float* zbuf  = (float*)w;  w += (size_t)B*D*4;
    float* hbuf  = (float*)w;  w += (size_t)B*F*4;       // 512 KB
    float* u3buf = (float*)w;  w += (size_t)B*D*4;
    float* lgt   = (float*)w;  w += (size_t)B*V*4;       // 1 MB
    int*   tok   = (int*)w;    w += 256;
    int*   ctrl  = (int*)w;    w += 8*64*4;              // 2 KB barrier state

    float* out = (float*)d_out;

    hipMemsetAsync(ctrl, 0, 8*64*4, stream);
    k_setup_mem<<<64, 256, 0, stream>>>(prot, p1w, p1b, p2w, p2b, caw, cab, ca_o);
    k_fold_sa<<<256, 256, 0, stream>>>(saw, sab, wfold, bfold);
    k_e0 <<<512, 256, 0, stream>>>(emb, wfold, E0);
    k_pew<<<16, 256, 0, stream>>>(pe, wfold, bfold, peW);

    k_decode<<<256, 256, 0, stream>>>(
        wfold, bfold, E0, peW, ca_o, w1, b1, w2, b2, lng, lnb,
        outw, outb, itok, u1buf, zbuf, hbuf, u3buf, lgt, tok, ctrl, out);
}